// Round 3
// baseline (570.621 us; speedup 1.0000x reference)
//
#include <hip/hip_runtime.h>
#include <stdint.h>

// QLinear HQQ 4-bit: out = x @ dequant(W_q).T + bias
// M=8192 tokens, N=4096 out features, K=4096 in features, group=64 along K.
//
// R3: restructure gemm K-loop from the m97 2-barrier global_load_lds shape
// (plateau ~781 TF here; drain of vmcnt(0) before each barrier) into the
// AITER/hipBLASLt shape: global->VGPR prefetch (depth 2), MFMAs on current
// LDS buffer, ds_write of the previously-loaded tile into the alternate
// buffer AFTER the MFMAs, ONE __syncthreads per K-step. The ds_write's
// vmcnt wait targets loads issued a full iteration earlier (hidden); only
// the barrier's conservative drain touches this iteration's prefetch, which
// is ~a compute-span old (mostly L2-hit-complete).

typedef __attribute__((ext_vector_type(8))) _Float16 half8;
typedef __attribute__((ext_vector_type(4))) float f32x4;

#define M_DIM 8192
#define N_DIM 4096
#define K_DIM 4096

// ---------------- stage 1a: x fp32 -> f16 ----------------
__global__ __launch_bounds__(256) void cvt_x_f16(const float* __restrict__ x,
                                                 _Float16* __restrict__ y) {
  const size_t i = ((size_t)blockIdx.x * 256 + threadIdx.x) * 8;
  f32x4 a = *(const f32x4*)(x + i);
  f32x4 b = *(const f32x4*)(x + i + 4);
  half8 h;
  h[0] = (_Float16)a[0]; h[1] = (_Float16)a[1];
  h[2] = (_Float16)a[2]; h[3] = (_Float16)a[3];
  h[4] = (_Float16)b[0]; h[5] = (_Float16)b[1];
  h[6] = (_Float16)b[2]; h[7] = (_Float16)b[3];
  *(half8*)(y + i) = h;
}

// ---------------- stage 1b: dequant W_q -> f16 [N][K] ----------------
// Each thread reads 8 packed ints once and emits BOTH nibble halves:
// row o (hi nibble) and row o+2048 (lo nibble). Halves W_q read traffic.
__global__ __launch_bounds__(256) void deq_w_f16(const int* __restrict__ Wq,
                                                 const float* __restrict__ scale,
                                                 const float* __restrict__ zero,
                                                 _Float16* __restrict__ W) {
  const int idx = blockIdx.x * 256 + threadIdx.x;   // 0..1048575
  const int o  = idx >> 9;                          // hi row 0..2047
  const int kb = (idx & 511) << 3;                  // col start, step 8
  const int gh = (o << 6) + (kb >> 6);              // group for row o
  const int gl = gh + 131072;                       // group for row o+2048
  const int* src = Wq + (size_t)gh * 64 + (kb & 63);
  const int4 v0 = *(const int4*)src;
  const int4 v1 = *(const int4*)(src + 4);
  const float sh = scale[gh], nzh = -zero[gh] * sh;
  const float sl = scale[gl], nzl = -zero[gl] * sl;
  int raw[8] = {v0.x, v0.y, v0.z, v0.w, v1.x, v1.y, v1.z, v1.w};
  half8 h, l;
#pragma unroll
  for (int r = 0; r < 8; ++r) {
    h[r] = (_Float16)((float)((raw[r] >> 4) & 0xF) * sh + nzh);
    l[r] = (_Float16)((float)(raw[r] & 0xF) * sl + nzl);
  }
  *(half8*)(W + (size_t)o * K_DIM + kb) = h;
  *(half8*)(W + (size_t)(o + 2048) * K_DIM + kb) = l;
}

// ---------------- stage 2: f16 MFMA GEMM-BT, pipelined K-loop ----------------
// C[m][n] = sum_k A[m][k]*B[n][k] + bias[n].  A:[M][K] f16, B:[N][K] f16.
// Block 128x128, BK=32, 256 thr = 4 waves (64x64 quadrant each, 4x4 MFMAs of
// 16x16x32). LDS double buffer; XOR granule swizzle (phys = log ^ ((row>>1)&3))
// applied on the ds_write address; straight (coalesced) global fetch.
__global__ __launch_bounds__(256, 3) void gemm_f16_ws(const _Float16* __restrict__ A,
                                                      const _Float16* __restrict__ B,
                                                      const float* __restrict__ bias,
                                                      float* __restrict__ C) {
  __shared__ _Float16 As[2][128 * 32];   // 2 x 8 KB
  __shared__ _Float16 Bs[2][128 * 32];   // 2 x 8 KB

  const int tid  = threadIdx.x;
  const int wave = tid >> 6;
  const int lane = tid & 63;
  const int quad = lane >> 4;
  const int l16  = lane & 15;

  const int m0 = blockIdx.y * 128;
  const int n0 = blockIdx.x * 128;
  const int wm = (wave & 1) * 64;
  const int wn = (wave >> 1) * 64;

  // staging: thread t loads row t>>2, global col (t&3)*8 (straight, coalesced),
  // writes LDS at swizzled granule (t&3)^((t>>3)&3).
  const int srow = tid >> 2;
  const int scol = (tid & 3) << 3;
  const int wcol = (((tid & 3) ^ ((tid >> 3) & 3)) << 3);
  const _Float16* gA0 = A + (size_t)(m0 + srow) * K_DIM + scol;
  const _Float16* gA1 = gA0 + (size_t)64 * K_DIM;
  const _Float16* gB0 = B + (size_t)(n0 + srow) * K_DIM + scol;
  const _Float16* gB1 = gB0 + (size_t)64 * K_DIM;
  const int w0 = srow * 32 + wcol;        // rows 0..63 slot
  const int w1 = w0 + 64 * 32;            // rows 64..127 slot

  // fragment read un-swizzle (validated conflict-free in R2)
  const int gf_off = ((quad ^ ((l16 >> 1) & 3)) << 3);

  f32x4 acc[4][4] = {};
  half8 st0[4], st1[4];

  // ---- prologue: tile0 -> buf0 (through regs), tile1 -> st1 (in flight) ----
  st0[0] = *(const half8*)(gA0);
  st0[1] = *(const half8*)(gA1);
  st0[2] = *(const half8*)(gB0);
  st0[3] = *(const half8*)(gB1);
  *(half8*)(&As[0][w0]) = st0[0];
  *(half8*)(&As[0][w1]) = st0[1];
  *(half8*)(&Bs[0][w0]) = st0[2];
  *(half8*)(&Bs[0][w1]) = st0[3];
  st1[0] = *(const half8*)(gA0 + 32);
  st1[1] = *(const half8*)(gA1 + 32);
  st1[2] = *(const half8*)(gB0 + 32);
  st1[3] = *(const half8*)(gB1 + 32);
  __syncthreads();

  auto compute = [&](const _Float16* AS, const _Float16* BS) {
    half8 aF[4], bF[4];
#pragma unroll
    for (int i = 0; i < 4; ++i)
      aF[i] = *(const half8*)(AS + (wm + i * 16 + l16) * 32 + gf_off);
#pragma unroll
    for (int j = 0; j < 4; ++j)
      bF[j] = *(const half8*)(BS + (wn + j * 16 + l16) * 32 + gf_off);
#pragma unroll
    for (int i = 0; i < 4; ++i)
#pragma unroll
      for (int j = 0; j < 4; ++j)
        acc[i][j] = __builtin_amdgcn_mfma_f32_16x16x32_f16(aF[i], bF[j],
                                                           acc[i][j], 0, 0, 0);
  };

  // ---- main loop, 2x unrolled for compile-time buffer parity ----
  for (int k0 = 0; k0 < K_DIM; k0 += 64) {
    {  // even: compute tile k0 from buf0; stage st1 (k0+32) -> buf1;
       // prefetch k0+64 -> st0
      const int kp = (k0 + 64 < K_DIM) ? (k0 + 64) : 0;
      st0[0] = *(const half8*)(gA0 + kp);
      st0[1] = *(const half8*)(gA1 + kp);
      st0[2] = *(const half8*)(gB0 + kp);
      st0[3] = *(const half8*)(gB1 + kp);
      compute(As[0], Bs[0]);
      *(half8*)(&As[1][w0]) = st1[0];   // waits only st1's loads (1 iter old)
      *(half8*)(&As[1][w1]) = st1[1];
      *(half8*)(&Bs[1][w0]) = st1[2];
      *(half8*)(&Bs[1][w1]) = st1[3];
      __syncthreads();
    }
    {  // odd: compute tile k0+32 from buf1; stage st0 (k0+64) -> buf0;
       // prefetch k0+96 -> st1
      const int kp = (k0 + 96 < K_DIM) ? (k0 + 96) : 0;
      st1[0] = *(const half8*)(gA0 + kp);
      st1[1] = *(const half8*)(gA1 + kp);
      st1[2] = *(const half8*)(gB0 + kp);
      st1[3] = *(const half8*)(gB1 + kp);
      compute(As[1], Bs[1]);
      *(half8*)(&As[0][w0]) = st0[0];
      *(half8*)(&As[0][w1]) = st0[1];
      *(half8*)(&Bs[0][w0]) = st0[2];
      *(half8*)(&Bs[0][w1]) = st0[3];
      __syncthreads();
    }
  }

  // epilogue: D row = quad*4 + reg, col = l16
#pragma unroll
  for (int j = 0; j < 4; ++j) {
    const int n = n0 + wn + j * 16 + l16;
    const float bv = bias[n];
#pragma unroll
    for (int i = 0; i < 4; ++i) {
      const int m = m0 + wm + i * 16 + quad * 4;
      float* p = C + (size_t)m * N_DIM + n;
      f32x4 v = acc[i][j];
      p[0 * N_DIM] = v[0] + bv;
      p[1 * N_DIM] = v[1] + bv;
      p[2 * N_DIM] = v[2] + bv;
      p[3 * N_DIM] = v[3] + bv;
    }
  }
}

// ---------------- fallback: fused fp32 GEMM, no workspace ----------------
__global__ __launch_bounds__(256) void gemm_fp32_fallback(
    const float* __restrict__ x, const int* __restrict__ Wq,
    const float* __restrict__ scale, const float* __restrict__ zero,
    const float* __restrict__ bias, float* __restrict__ C) {
  __shared__ float As[64][16];
  __shared__ float Bs[64][16];
  const int tid = threadIdx.x;
  const int m0 = blockIdx.y * 64;
  const int n0 = blockIdx.x * 64;
  const int tx = tid & 15;
  const int ty = tid >> 4;
  const int lr = tid >> 2;
  const int lc = (tid & 3) << 2;

  float acc[4][4] = {};

  for (int k0 = 0; k0 < K_DIM; k0 += 16) {
    __syncthreads();
    *(f32x4*)&As[lr][lc] = *(const f32x4*)(x + (size_t)(m0 + lr) * K_DIM + k0 + lc);
    {
      const int o = n0 + lr;
      const int k = k0 + lc;
      const int g = (o << 6) + (k >> 6);
      const bool hi = (o < 2048);
      const int* src = Wq + (size_t)(hi ? g : g - 131072) * 64 + (k & 63);
      const int4 v = *(const int4*)src;
      const float s = scale[g];
      const float nz = -zero[g] * s;
      f32x4 b;
      if (hi) {
        b[0] = (float)((v.x >> 4) & 0xF) * s + nz;
        b[1] = (float)((v.y >> 4) & 0xF) * s + nz;
        b[2] = (float)((v.z >> 4) & 0xF) * s + nz;
        b[3] = (float)((v.w >> 4) & 0xF) * s + nz;
      } else {
        b[0] = (float)(v.x & 0xF) * s + nz;
        b[1] = (float)(v.y & 0xF) * s + nz;
        b[2] = (float)(v.z & 0xF) * s + nz;
        b[3] = (float)(v.w & 0xF) * s + nz;
      }
      *(f32x4*)&Bs[lr][lc] = b;
    }
    __syncthreads();
#pragma unroll
    for (int kk = 0; kk < 16; ++kk) {
      float a[4], b[4];
#pragma unroll
      for (int r = 0; r < 4; ++r) a[r] = As[ty * 4 + r][kk];
#pragma unroll
      for (int c = 0; c < 4; ++c) b[c] = Bs[tx * 4 + c][kk];
#pragma unroll
      for (int r = 0; r < 4; ++r)
#pragma unroll
        for (int c = 0; c < 4; ++c) acc[r][c] += a[r] * b[c];
    }
  }
#pragma unroll
  for (int r = 0; r < 4; ++r)
#pragma unroll
    for (int c = 0; c < 4; ++c) {
      const int n = n0 + tx * 4 + c;
      C[(size_t)(m0 + ty * 4 + r) * N_DIM + n] = acc[r][c] + bias[n];
    }
}

extern "C" void kernel_launch(void* const* d_in, const int* in_sizes, int n_in,
                              void* d_out, int out_size, void* d_ws, size_t ws_size,
                              hipStream_t stream) {
  const float* x     = (const float*)d_in[0];
  const int*   Wq    = (const int*)d_in[1];
  const float* scale = (const float*)d_in[2];
  const float* zero  = (const float*)d_in[3];
  const float* bias  = (const float*)d_in[4];
  float* out = (float*)d_out;

  const size_t xh_bytes = (size_t)M_DIM * K_DIM * 2;  // 64 MB
  const size_t wh_bytes = (size_t)N_DIM * K_DIM * 2;  // 32 MB

  if (ws_size >= xh_bytes + wh_bytes) {
    _Float16* xh = (_Float16*)d_ws;
    _Float16* wh = (_Float16*)((char*)d_ws + xh_bytes);
    cvt_x_f16<<<M_DIM * K_DIM / (256 * 8), 256, 0, stream>>>(x, xh);
    deq_w_f16<<<N_DIM * K_DIM / (2 * 256 * 8), 256, 0, stream>>>(Wq, scale, zero, wh);
    dim3 grid(N_DIM / 128, M_DIM / 128);  // (32, 64)
    gemm_f16_ws<<<grid, 256, 0, stream>>>(xh, wh, bias, out);
  } else {
    dim3 grid(N_DIM / 64, M_DIM / 64);    // (64, 128)
    gemm_fp32_fallback<<<grid, 256, 0, stream>>>(x, Wq, scale, zero, bias, out);
  }
}